// Round 7
// baseline (894.152 us; speedup 1.0000x reference)
//
#include <hip/hip_runtime.h>

typedef unsigned short ushort_t;
typedef unsigned int uint32;

typedef __bf16 bf16x8 __attribute__((ext_vector_type(8)));
typedef float f32x4 __attribute__((ext_vector_type(4)));

#define DEVI static __device__ __forceinline__

constexpr int N_ = 50000;
constexpr int E_ = 800000;

// workspace byte offsets
constexpr size_t OFF_SUM1 = 0;               // f32 N*128
constexpr size_t OFF_SUM2 = 25600000;        // f32 N*64
constexpr size_t OFF_CNT  = 38400000;        // f32 N
constexpr size_t ZERO_BYTES = 38600000;
constexpr size_t OFF_H    = 38600192;        // bf16 N*128 (dead after edge2)
constexpr size_t OFF_XB   = 51400192;        // bf16 N*64 x_nodes (dead after edge1)
constexpr size_t OFF_G    = 51400192;        // bf16 N*64 (aliases XB; written at node2)
constexpr size_t OFF_WTH  = 57800192;        // bf16 16*256 head weights^T
constexpr size_t OFF_E16  = 57808384;        // bf16 emb 3*16
constexpr size_t OFF_FLAG = 57808512;        // int32 x 4
constexpr size_t OFF_SRC  = 57808640;        // int32 E
constexpr size_t OFF_DST  = 61008640;        // int32 E
constexpr size_t OFF_MODE = 64208640;        // int32 N -> ends 64,408,640
constexpr size_t WS_NEED  = 64408640;
constexpr size_t OFF_Y1   = 0;               // bf16 N*256 (aliases SUM1; mlp phase only)
constexpr size_t OFF_Y2   = 25600000;        // bf16 N*256 (aliases SUM2/CNT/H-prefix; dead then)

DEVI ushort_t f2b(float f){ union { float f; uint32 u; } x; x.f = f;
  uint32 r = (x.u + 0x7fffu + ((x.u >> 16) & 1u)) >> 16; return (ushort_t)r; }

DEVI bf16x8 cvt8(const float* p){
  f32x4 u = *(const f32x4*)p, v = *(const f32x4*)(p + 4);
  bf16x8 r;
#pragma unroll
  for (int j = 0; j < 4; ++j) r[j] = (__bf16)u[j];
#pragma unroll
  for (int j = 0; j < 4; ++j) r[4+j] = (__bf16)v[j];
  return r;
}

// ---- diagnostic: encode a metadata-anomaly code into out[0] (f32) ----
__global__ void k_code(float* out, float code){
  if (threadIdx.x == 0 && blockIdx.x == 0) out[0] = code;
}

// ---- detect int64 vs int32 layout of edge_index / mode (proven int32; keep for safety) ----
__launch_bounds__(256)
__global__ void k_detect(const int* __restrict__ ei, const int* __restrict__ mo,
                         int* __restrict__ flags)
{
  __shared__ int red[2];
  if (threadIdx.x == 0) { red[0] = 0; red[1] = 0; }
  __syncthreads();
  int a = 0, b = 0;
  for (int i = threadIdx.x; i < 4096; i += 256) a |= ei[2*i + 1];
  for (int i = threadIdx.x; i < 2048; i += 256) b |= mo[2*i + 1];
  atomicOr(&red[0], a);
  atomicOr(&red[1], b);
  __syncthreads();
  if (threadIdx.x == 0) { flags[0] = (red[0] == 0) ? 1 : 0; flags[1] = (red[1] == 0) ? 1 : 0; }
}

__launch_bounds__(256)
__global__ void k_cvt(const int* __restrict__ ei, const int* __restrict__ mo,
                      const int* __restrict__ flags,
                      int* __restrict__ SRC, int* __restrict__ DST, int* __restrict__ MODE)
{
  const int fE = flags[0], fM = flags[1];
  const int g = gridDim.x * 256;
  for (int e = blockIdx.x*256 + threadIdx.x; e < E_; e += g) {
    SRC[e] = fE ? ei[2*e]        : ei[e];
    DST[e] = fE ? ei[2*E_ + 2*e] : ei[E_ + e];
  }
  for (int n = blockIdx.x*256 + threadIdx.x; n < N_; n += g) {
    MODE[n] = fM ? mo[2*n] : mo[n];
  }
}

// ---- prep: x_nodes f32->bf16, head W^T bf16, emb bf16 ----
__launch_bounds__(256)
__global__ void k_prep(const float* __restrict__ xn, const float* __restrict__ wm,
                       const float* __restrict__ wsw, const float* __restrict__ emb,
                       ushort_t* __restrict__ xb, ushort_t* __restrict__ wth,
                       ushort_t* __restrict__ e16)
{
  int i = blockIdx.x * 256 + threadIdx.x;
  if (i < N_*64) {
    xb[i] = f2b(xn[i]);
  } else if (i < N_*64 + 4096) {
    int j = i - N_*64; int n = j >> 8, k = j & 255;
    wth[j] = f2b(n < 8 ? wm[k*8 + n] : wsw[k*8 + (n - 8)]);
  } else if (i < N_*64 + 4096 + 48) {
    int j = i - (N_*64 + 4096);
    e16[j] = f2b(emb[j]);
  }
}

// ------- edge layer 1 (MFMA): t = relu(cat[x_dst,x_src]@W1a + b1a); atomic -> sum1, cnt ----
__launch_bounds__(256)
__global__ void k_edge1(const ushort_t* __restrict__ xb,
                        const int* __restrict__ SRC, const int* __restrict__ DST,
                        const float* __restrict__ w1a, const float* __restrict__ b1a,
                        float* __restrict__ sum1, float* __restrict__ cnt)
{
  __shared__ __attribute__((aligned(16))) ushort_t Wt[128*136];
  const int tid = threadIdx.x;
  for (int i = tid; i < 128*128; i += 256) { int k = i >> 7, n = i & 127; Wt[n*136 + k] = f2b(w1a[i]); }
  __syncthreads();
  const int wave = tid >> 6, lane = tid & 63;
  const int p = lane & 15, q = lane >> 4;
  bf16x8 bfr[8][4];
#pragma unroll
  for (int nt = 0; nt < 8; ++nt)
#pragma unroll
    for (int s = 0; s < 4; ++s)
      bfr[nt][s] = *(const bf16x8*)&Wt[(nt*16 + p)*136 + s*32 + q*8];
  float bias[8];
#pragma unroll
  for (int nt = 0; nt < 8; ++nt) bias[nt] = b1a[nt*16 + p];
  const int nwaves = gridDim.x * 4;
  for (int t = blockIdx.x*4 + wave; t < E_/16; t += nwaves) {
    const int base = t * 16;
    const int d_p = DST[base + p];
    const int s_p = SRC[base + p];
    const ushort_t* xd = xb + (size_t)d_p * 64;
    const ushort_t* xs = xb + (size_t)s_p * 64;
    bf16x8 afr[4];
    afr[0] = *(const bf16x8*)(xd + q*8);
    afr[1] = *(const bf16x8*)(xd + 32 + q*8);
    afr[2] = *(const bf16x8*)(xs + q*8);
    afr[3] = *(const bf16x8*)(xs + 32 + q*8);
    if (q == 0) atomicAdd(&cnt[d_p], 1.0f);
    f32x4 acc[8];
#pragma unroll
    for (int nt = 0; nt < 8; ++nt) acc[nt] = (f32x4){0.f,0.f,0.f,0.f};
#pragma unroll
    for (int nt = 0; nt < 8; ++nt)
#pragma unroll
      for (int s = 0; s < 4; ++s)
        acc[nt] = __builtin_amdgcn_mfma_f32_16x16x32_bf16(afr[s], bfr[nt][s], acc[nt], 0, 0, 0);
    int drow[4];
#pragma unroll
    for (int r = 0; r < 4; ++r) drow[r] = __shfl(d_p, q*4 + r);
#pragma unroll
    for (int nt = 0; nt < 8; ++nt)
#pragma unroll
      for (int r = 0; r < 4; ++r) {
        float v = fmaxf(acc[nt][r] + bias[nt], 0.0f);
        atomicAdd(&sum1[(size_t)drow[r]*128 + nt*16 + p], v);
      }
  }
}

// ---------------- node layer 1: h = relu(mean1 @ W1b + b1b) (0 if cnt==0) -> bf16 ----
__launch_bounds__(256)
__global__ void k_node1(const float* __restrict__ sum1, const float* __restrict__ cnt,
                        const float* __restrict__ w1b, const float* __restrict__ b1b,
                        ushort_t* __restrict__ h)
{
  int n = blockIdx.x * 256 + threadIdx.x;
  if (n >= N_) return;
  float c = cnt[n];
  float inv = 1.0f / fmaxf(c, 1.0f);
  bool live = c > 0.0f;
  const f32x4* row = (const f32x4*)(sum1 + (size_t)n*128);
#pragma unroll
  for (int half = 0; half < 2; ++half) {
    float dot[64];
#pragma unroll
    for (int j = 0; j < 64; ++j) dot[j] = 0.0f;
    for (int k4 = 0; k4 < 32; ++k4) {
      f32x4 v = row[k4];
#pragma unroll
      for (int e = 0; e < 4; ++e) {
        float vk = v[e];
        const float* wrow = &w1b[(k4*4 + e)*128 + half*64];
#pragma unroll
        for (int j = 0; j < 64; ++j) dot[j] = fmaf(vk, wrow[j], dot[j]);
      }
    }
    uint32* dst = (uint32*)(h + (size_t)n*128 + half*64);
#pragma unroll
    for (int j = 0; j < 32; ++j) {
      float a = live ? fmaxf(b1b[half*64 + 2*j]     + inv*dot[2*j],   0.f) : 0.f;
      float b = live ? fmaxf(b1b[half*64 + 2*j + 1] + inv*dot[2*j+1], 0.f) : 0.f;
      dst[j] = (uint32)f2b(a) | ((uint32)f2b(b) << 16);
    }
  }
}

// ------- edge layer 2 (MFMA): t2 = relu(cat[h_dst,h_src]@W2a + b2a); atomic -> sum2 ----
__launch_bounds__(256)
__global__ void k_edge2(const ushort_t* __restrict__ h,
                        const int* __restrict__ SRC, const int* __restrict__ DST,
                        const float* __restrict__ w2a, const float* __restrict__ b2a,
                        float* __restrict__ sum2)
{
  __shared__ __attribute__((aligned(16))) ushort_t Wt[64*264];
  const int tid = threadIdx.x;
  for (int i = tid; i < 256*64; i += 256) { int k = i >> 6, n = i & 63; Wt[n*264 + k] = f2b(w2a[i]); }
  __syncthreads();
  const int wave = tid >> 6, lane = tid & 63;
  const int p = lane & 15, q = lane >> 4;
  bf16x8 bfr[4][8];
#pragma unroll
  for (int nt = 0; nt < 4; ++nt)
#pragma unroll
    for (int s = 0; s < 8; ++s)
      bfr[nt][s] = *(const bf16x8*)&Wt[(nt*16 + p)*264 + s*32 + q*8];
  float bias[4];
#pragma unroll
  for (int nt = 0; nt < 4; ++nt) bias[nt] = b2a[nt*16 + p];
  const int nwaves = gridDim.x * 4;
  for (int t = blockIdx.x*4 + wave; t < E_/16; t += nwaves) {
    const int base = t * 16;
    const int d_p = DST[base + p];
    const int s_p = SRC[base + p];
    const ushort_t* hd = h + (size_t)d_p * 128;
    const ushort_t* hs = h + (size_t)s_p * 128;
    bf16x8 afr[8];
#pragma unroll
    for (int s = 0; s < 4; ++s) afr[s]     = *(const bf16x8*)(hd + s*32 + q*8);
#pragma unroll
    for (int s = 0; s < 4; ++s) afr[4 + s] = *(const bf16x8*)(hs + s*32 + q*8);
    f32x4 acc[4];
#pragma unroll
    for (int nt = 0; nt < 4; ++nt) acc[nt] = (f32x4){0.f,0.f,0.f,0.f};
#pragma unroll
    for (int nt = 0; nt < 4; ++nt)
#pragma unroll
      for (int s = 0; s < 8; ++s)
        acc[nt] = __builtin_amdgcn_mfma_f32_16x16x32_bf16(afr[s], bfr[nt][s], acc[nt], 0, 0, 0);
    int drow[4];
#pragma unroll
    for (int r = 0; r < 4; ++r) drow[r] = __shfl(d_p, q*4 + r);
#pragma unroll
    for (int nt = 0; nt < 4; ++nt)
#pragma unroll
      for (int r = 0; r < 4; ++r) {
        float v = fmaxf(acc[nt][r] + bias[nt], 0.0f);
        atomicAdd(&sum2[(size_t)drow[r]*64 + nt*16 + p], v);
      }
  }
}

// ---------------- node layer 2: g = mean2 @ W2b + b2b (0 if cnt==0), no relu -> bf16 ----
__launch_bounds__(256)
__global__ void k_node2(const float* __restrict__ sum2, const float* __restrict__ cnt,
                        const float* __restrict__ w2b, const float* __restrict__ b2b,
                        ushort_t* __restrict__ g)
{
  int n = blockIdx.x * 256 + threadIdx.x;
  if (n >= N_) return;
  float c = cnt[n];
  float inv = 1.0f / fmaxf(c, 1.0f);
  bool live = c > 0.0f;
  const f32x4* row = (const f32x4*)(sum2 + (size_t)n*64);
  float dot[64];
#pragma unroll
  for (int j = 0; j < 64; ++j) dot[j] = 0.0f;
  for (int k4 = 0; k4 < 16; ++k4) {
    f32x4 v = row[k4];
#pragma unroll
    for (int e = 0; e < 4; ++e) {
      float vk = v[e];
      const float* wrow = &w2b[(k4*4 + e)*64];
#pragma unroll
      for (int j = 0; j < 64; ++j) dot[j] = fmaf(vk, wrow[j], dot[j]);
    }
  }
  uint32* dst = (uint32*)(g + (size_t)n*64);
#pragma unroll
  for (int j = 0; j < 32; ++j) {
    float a = live ? (b2b[2*j]     + inv*dot[2*j])   : 0.f;
    float b = live ? (b2b[2*j + 1] + inv*dot[2*j+1]) : 0.f;
    dst[j] = (uint32)f2b(a) | ((uint32)f2b(b) << 16);
  }
}

// ---------------- mlp1 (MFMA): y1 = relu([state,g,me] @ W1 + b1); half-column blocks ----
__launch_bounds__(256)
__global__ void k_mlp1(const float* __restrict__ state, const ushort_t* __restrict__ gbuf,
                       const ushort_t* __restrict__ e16, const int* __restrict__ MODE,
                       const float* __restrict__ b1f, const float* __restrict__ w1,
                       ushort_t* __restrict__ y1)
{
  __shared__ __attribute__((aligned(16))) ushort_t Wt[128*168];
  const int tid = threadIdx.x;
  const int cb = (blockIdx.x & 1) * 128;
  for (int i = tid; i < 128*160; i += 256) {
    int n = i / 160, k = i - n*160;
    Wt[n*168 + k] = (k < 144) ? f2b(w1[k*256 + cb + n]) : (ushort_t)0;
  }
  __syncthreads();
  const int wave = tid >> 6, lane = tid & 63;
  const int p = lane & 15, q = lane >> 4;
  float bias[8];
#pragma unroll
  for (int nt = 0; nt < 8; ++nt) bias[nt] = b1f[cb + nt*16 + p];
  bf16x8 zed;
#pragma unroll
  for (int j = 0; j < 8; ++j) zed[j] = (__bf16)0.0f;
  const int nwaves = (gridDim.x >> 1) * 4;
  for (int t = (blockIdx.x >> 1)*4 + wave; t < N_/16; t += nwaves) {
    const int base = t * 16;
    const int node = base + p;
    bf16x8 afr[5];
    afr[0] = cvt8(state + (size_t)node*64 + q*8);
    afr[1] = cvt8(state + (size_t)node*64 + 32 + q*8);
    afr[2] = *(const bf16x8*)(gbuf + (size_t)node*64 + q*8);
    afr[3] = *(const bf16x8*)(gbuf + (size_t)node*64 + 32 + q*8);
    afr[4] = (q < 2) ? *(const bf16x8*)(e16 + (size_t)MODE[node]*16 + q*8) : zed;
    f32x4 acc[8];
#pragma unroll
    for (int nt = 0; nt < 8; ++nt) acc[nt] = (f32x4){0.f,0.f,0.f,0.f};
#pragma unroll
    for (int nt = 0; nt < 8; ++nt)
#pragma unroll
      for (int s = 0; s < 5; ++s) {
        bf16x8 b = *(const bf16x8*)&Wt[(nt*16 + p)*168 + s*32 + q*8];
        acc[nt] = __builtin_amdgcn_mfma_f32_16x16x32_bf16(afr[s], b, acc[nt], 0, 0, 0);
      }
#pragma unroll
    for (int nt = 0; nt < 8; ++nt)
#pragma unroll
      for (int r = 0; r < 4; ++r) {
        float v = fmaxf(acc[nt][r] + bias[nt], 0.0f);
        y1[(size_t)(base + q*4 + r)*256 + cb + nt*16 + p] = f2b(v);
      }
  }
}

// ---------------- mlp2 (MFMA): y2 = relu(y1 @ W2 + b2); half-column blocks ----
__launch_bounds__(256)
__global__ void k_mlp2(const ushort_t* __restrict__ y1, const float* __restrict__ w2,
                       const float* __restrict__ b2f, ushort_t* __restrict__ y2)
{
  __shared__ __attribute__((aligned(16))) ushort_t Wt[128*264];
  const int tid = threadIdx.x;
  const int cb = (blockIdx.x & 1) * 128;
  for (int i = tid; i < 128*256; i += 256) {
    int n = i >> 8, k = i & 255;
    Wt[n*264 + k] = f2b(w2[k*256 + cb + n]);
  }
  __syncthreads();
  const int wave = tid >> 6, lane = tid & 63;
  const int p = lane & 15, q = lane >> 4;
  float bias[8];
#pragma unroll
  for (int nt = 0; nt < 8; ++nt) bias[nt] = b2f[cb + nt*16 + p];
  const int nwaves = (gridDim.x >> 1) * 4;
  for (int t = (blockIdx.x >> 1)*4 + wave; t < N_/16; t += nwaves) {
    const int base = t * 16;
    bf16x8 afr[8];
#pragma unroll
    for (int s = 0; s < 8; ++s)
      afr[s] = *(const bf16x8*)(y1 + (size_t)(base + p)*256 + s*32 + q*8);
    f32x4 acc[8];
#pragma unroll
    for (int nt = 0; nt < 8; ++nt) acc[nt] = (f32x4){0.f,0.f,0.f,0.f};
#pragma unroll
    for (int nt = 0; nt < 8; ++nt)
#pragma unroll
      for (int s = 0; s < 8; ++s) {
        bf16x8 b = *(const bf16x8*)&Wt[(nt*16 + p)*264 + s*32 + q*8];
        acc[nt] = __builtin_amdgcn_mfma_f32_16x16x32_bf16(afr[s], b, acc[nt], 0, 0, 0);
      }
#pragma unroll
    for (int nt = 0; nt < 8; ++nt)
#pragma unroll
      for (int r = 0; r < 4; ++r) {
        float v = fmaxf(acc[nt][r] + bias[nt], 0.0f);
        y2[(size_t)(base + q*4 + r)*256 + cb + nt*16 + p] = f2b(v);
      }
  }
}

// ---------------- heads (MFMA): mean = y2@Wm+bm ; log_std = clip(y2@Ws+bs, -20, 2); f32 out ----
__launch_bounds__(256)
__global__ void k_heads(const ushort_t* __restrict__ y2, const ushort_t* __restrict__ wth,
                        const float* __restrict__ bm, const float* __restrict__ bs,
                        float* __restrict__ out)
{
  const int tid = threadIdx.x;
  const int wave = tid >> 6, lane = tid & 63;
  const int p = lane & 15, q = lane >> 4;
  bf16x8 bfr[8];
#pragma unroll
  for (int s = 0; s < 8; ++s)
    bfr[s] = *(const bf16x8*)(wth + (size_t)p*256 + s*32 + q*8);
  float bias = (p < 8) ? bm[p] : bs[p - 8];
  const int nwaves = gridDim.x * 4;
  for (int t = blockIdx.x*4 + wave; t < N_/16; t += nwaves) {
    const int base = t * 16;
    f32x4 acc = (f32x4){0.f,0.f,0.f,0.f};
#pragma unroll
    for (int s = 0; s < 8; ++s) {
      bf16x8 a = *(const bf16x8*)(y2 + (size_t)(base + p)*256 + s*32 + q*8);
      acc = __builtin_amdgcn_mfma_f32_16x16x32_bf16(a, bfr[s], acc, 0, 0, 0);
    }
#pragma unroll
    for (int r = 0; r < 4; ++r) {
      int node = base + q*4 + r;
      float v = acc[r] + bias;
      if (p < 8) {
        out[(size_t)node*8 + p] = v;
      } else {
        v = fminf(fmaxf(v, -20.f), 2.f);
        out[(size_t)N_*8 + (size_t)node*8 + (p - 8)] = v;
      }
    }
  }
}

extern "C" void kernel_launch(void* const* d_in, const int* in_sizes, int n_in,
                              void* d_out, int out_size, void* d_ws, size_t ws_size,
                              hipStream_t stream)
{
  float* out = (float*)d_out;

  // metadata tripwires (never fired through round 6; keep as insurance)
  float code = 0.0f;
  if      (n_in != 21)                 code = 1.0e6f;
  else if (in_sizes[0]  != 3200000)    code = 2.0e6f;
  else if (in_sizes[1]  != 3200000)    code = 3.0e6f;
  else if (in_sizes[2]  != 1600000)    code = 4.0e6f;
  else if (in_sizes[3]  != 50000)      code = 5.0e6f;
  else if (in_sizes[4]  != 16384)      code = 6.0e6f;
  else if (in_sizes[13] != 36864)      code = 7.0e6f;
  else if (in_sizes[15] != 65536)      code = 8.0e6f;
  else if (in_sizes[17] != 2048)       code = 9.0e6f;
  else if (out_size     != 800000)     code = 1.0e7f;
  else if (ws_size      < WS_NEED)     code = 1.1e7f;
  if (code != 0.0f) {
    k_code<<<1, 64, 0, stream>>>(out, code);
    return;
  }

  const float* state = (const float*)d_in[0];
  const float* xn    = (const float*)d_in[1];
  const int*   ei    = (const int*)d_in[2];
  const int*   mo    = (const int*)d_in[3];
  const float* w1a   = (const float*)d_in[4];
  const float* b1a   = (const float*)d_in[5];
  const float* w1b   = (const float*)d_in[6];
  const float* b1b   = (const float*)d_in[7];
  const float* w2a   = (const float*)d_in[8];
  const float* b2a   = (const float*)d_in[9];
  const float* w2b   = (const float*)d_in[10];
  const float* b2b   = (const float*)d_in[11];
  const float* emb   = (const float*)d_in[12];
  const float* w1    = (const float*)d_in[13];
  const float* b1    = (const float*)d_in[14];
  const float* w2    = (const float*)d_in[15];
  const float* b2    = (const float*)d_in[16];
  const float* wm    = (const float*)d_in[17];
  const float* bm    = (const float*)d_in[18];
  const float* wsw   = (const float*)d_in[19];
  const float* bs    = (const float*)d_in[20];

  char* ws = (char*)d_ws;
  float*    sum1 = (float*)(ws + OFF_SUM1);
  float*    sum2 = (float*)(ws + OFF_SUM2);
  float*    cnt  = (float*)(ws + OFF_CNT);
  ushort_t* H    = (ushort_t*)(ws + OFF_H);
  ushort_t* XB   = (ushort_t*)(ws + OFF_XB);
  ushort_t* G    = (ushort_t*)(ws + OFF_G);
  ushort_t* Y1   = (ushort_t*)(ws + OFF_Y1);
  ushort_t* Y2   = (ushort_t*)(ws + OFF_Y2);
  ushort_t* WTH  = (ushort_t*)(ws + OFF_WTH);
  ushort_t* E16  = (ushort_t*)(ws + OFF_E16);
  int*      FLG  = (int*)(ws + OFF_FLAG);
  int*      SRC  = (int*)(ws + OFF_SRC);
  int*      DST  = (int*)(ws + OFF_DST);
  int*      MODE = (int*)(ws + OFF_MODE);

  hipMemsetAsync(ws, 0, ZERO_BYTES, stream);
  k_detect<<<1,    256, 0, stream>>>(ei, mo, FLG);
  k_cvt   <<<3200, 256, 0, stream>>>(ei, mo, FLG, SRC, DST, MODE);
  k_prep  <<<12517,256, 0, stream>>>(xn, wm, wsw, emb, XB, WTH, E16);
  k_edge1 <<<1024, 256, 0, stream>>>(XB, SRC, DST, w1a, b1a, sum1, cnt);
  k_node1 <<<196,  256, 0, stream>>>(sum1, cnt, w1b, b1b, H);
  k_edge2 <<<1024, 256, 0, stream>>>(H, SRC, DST, w2a, b2a, sum2);
  k_node2 <<<196,  256, 0, stream>>>(sum2, cnt, w2b, b2b, G);
  k_mlp1  <<<256,  256, 0, stream>>>(state, G, E16, MODE, b1, w1, Y1);
  k_mlp2  <<<256,  256, 0, stream>>>(Y1, w2, b2, Y2);
  k_heads <<<128,  256, 0, stream>>>(Y2, WTH, bm, bs, out);
}